// Round 2
// baseline (3143.683 us; speedup 1.0000x reference)
//
#include <hip/hip_runtime.h>
#include <hip/hip_fp16.h>

#define NT    365
#define NGRID 1000
#define NXI   20
#define HID   256
#define GATES 1024
#define MROWS 365000          // NT*NGRID
#define MBLK  5704            // ceil(MROWS/64)
#define MPAD  (MBLK * 64)
#define NCL   63              // clusters (16 pts each, last ragged)
#define CPTS  16
#define HX_TOT ((size_t)NT * NCL * 1024)   // u64 slots, deep buffer (188MB)
#define HX_ZERO ((size_t)NCL * 1024)       // t=0 region: zeros (h_0 = 0)

typedef _Float16 half8 __attribute__((ext_vector_type(8)));
typedef float floatx4 __attribute__((ext_vector_type(4)));
typedef unsigned long long u64;
typedef u64 u64x2 __attribute__((ext_vector_type(2)));

#define SENT 0xFFFFFFFFFFFFFFFFull   // 4x fp16 -NaN: unreachable (|h|<=1)

// Module-scope globals (d_ws too small). Fully rewritten/reset every launch.
__device__ _Float16 g_gx[(size_t)MPAD * GATES];   // gx, block-local column layout
__device__ _Float16 g_wif[64 * 8 * 512];          // W_ih B-frags (global n-tiles)
__device__ _Float16 g_whf[2 * 32 * 8 * 64 * 8];   // W_hh B-frags, split by rec block
// h exchange, A-FRAGMENT ORDER, plane-split: chunk[(ks)*64 + lane] (+512 for
// the 2nd u64 of the half8). Sentinel protocol; deep t-indexed buffer.
__device__ u64 g_hx[HX_TOT];

__device__ __forceinline__ float fsig(float x) {
  return __fdividef(1.f, 1.f + __expf(-x));
}
__device__ __forceinline__ float ftanh(float x) {
  return 1.f - __fdividef(2.f, __expf(2.f * x) + 1.f);
}

// ---- pack weights into MFMA B-fragment layouts ----------------------------
// B-frag 16x16x32: lane holds B[n=tile*16+(lane&15)][k=ks*32+(lane>>4)*8+j]
__global__ __launch_bounds__(256) void pack_wf_kernel(
    const float* __restrict__ W_ih, const float* __restrict__ W_hh) {
  const int gid = blockIdx.x * 256 + threadIdx.x;   // 0..65535
  const float* src;
  _Float16* dst;
  int n, k0, lane;
  if (gid < 32768) {                 // W_ih -> g_wif, global n-tile layout
    const int tile = gid >> 9;
    const int ks   = (gid >> 6) & 7;
    lane = gid & 63;
    n  = tile * 16 + (lane & 15);
    k0 = ks * 32 + (lane >> 4) * 8;
    src = W_ih + n * HID + k0;
    dst = g_wif + ((size_t)(tile * 8 + ks) * 64 + lane) * 8;
  } else {                           // W_hh -> g_whf, [b][ltile][ks global]
    const int rem = gid - 32768;
    const int b2  = rem >> 14;       // owning rec block (dim half)
    const int lt  = (rem >> 9) & 31; // local tile = tau*8 + sub
    const int ks  = (rem >> 6) & 7;
    lane = rem & 63;
    const int nt = (lt >> 3) * 16 + b2 * 8 + (lt & 7);
    n  = nt * 16 + (lane & 15);
    k0 = ks * 32 + (lane >> 4) * 8;
    src = W_hh + n * HID + k0;
    dst = g_whf + ((size_t)((b2 * 32 + lt) * 8 + ks) * 64 + lane) * 8;
  }
  const float4 a = *(const float4*)(src);
  const float4 b = *(const float4*)(src + 4);
  half8 h;
  h[0] = (_Float16)a.x; h[1] = (_Float16)a.y; h[2] = (_Float16)a.z; h[3] = (_Float16)a.w;
  h[4] = (_Float16)b.x; h[5] = (_Float16)b.y; h[6] = (_Float16)b.z; h[7] = (_Float16)b.w;
  *(half8*)dst = h;
}

// ---- gx = relu(x@W_in.T+b_in) @ W_ih.T + (b_ih+b_hh), fused ---------------
// Output column layout per row: phi(g) = b*512 + tau*128 + (g&127).
// PREAMBLE (fused former init_kernel): sentinel-fill g_hx + zero y.
__global__ __launch_bounds__(256, 2) void gx_kernel(
    const float* __restrict__ x, const float* __restrict__ W_in,
    const float* __restrict__ b_in, const float* __restrict__ b_ih,
    const float* __restrict__ b_hh, float* __restrict__ y) {
  {
    const size_t gid = (size_t)blockIdx.x * 256 + threadIdx.x;
    const size_t TT  = (size_t)MBLK * 256;
    for (size_t j = gid; j < HX_TOT; j += TT)
      g_hx[j] = (j < HX_ZERO) ? 0ull : SENT;
    if (gid < MROWS) y[gid] = 0.f;
  }

  __shared__ float s_x[64 * NXI];
  __shared__ _Float16 s_x0[64 * 264];
  __shared__ _Float16 s_out[64 * 264];

  const int tid  = threadIdx.x;
  const int lane = tid & 63;
  const int w    = tid >> 6;
  const int m0   = blockIdx.x * 64;

  #pragma unroll
  for (int i = 0; i < 5; ++i) {
    const int idx = i * 256 + tid;
    size_t g = (size_t)m0 * NXI + idx;
    const size_t gmax = (size_t)MROWS * NXI - 1;
    if (g > gmax) g = gmax;
    s_x[idx] = x[g];
  }
  float wv[NXI];
  #pragma unroll
  for (int k = 0; k < NXI; ++k) wv[k] = W_in[tid * NXI + k];
  const float bv = b_in[tid];
  __syncthreads();

  for (int r = 0; r < 64; ++r) {
    float acc = bv;
    #pragma unroll
    for (int qq = 0; qq < 5; ++qq) {
      const float4 xa = *(const float4*)&s_x[r * NXI + qq * 4];
      acc += xa.x * wv[qq * 4 + 0] + xa.y * wv[qq * 4 + 1] +
             xa.z * wv[qq * 4 + 2] + xa.w * wv[qq * 4 + 3];
    }
    s_x0[r * 264 + tid] = (_Float16)fmaxf(acc, 0.f);
  }
  __syncthreads();

  for (int ng = 0; ng < 4; ++ng) {    // 4 groups of 256 gates
    floatx4 acc[4][4];
    #pragma unroll
    for (int mi = 0; mi < 4; ++mi)
      #pragma unroll
      for (int ni = 0; ni < 4; ++ni) acc[mi][ni] = (floatx4){0.f, 0.f, 0.f, 0.f};

    #pragma unroll
    for (int ks = 0; ks < 8; ++ks) {
      half8 a[4], bfr[4];
      #pragma unroll
      for (int mi = 0; mi < 4; ++mi)
        a[mi] = *(const half8*)&s_x0[(mi * 16 + (lane & 15)) * 264 + ks * 32 + (lane >> 4) * 8];
      #pragma unroll
      for (int ni = 0; ni < 4; ++ni) {
        const int nt = ng * 16 + w * 4 + ni;
        bfr[ni] = *(const half8*)(g_wif + ((size_t)(nt * 8 + ks) * 64 + lane) * 8);
      }
      #pragma unroll
      for (int mi = 0; mi < 4; ++mi)
        #pragma unroll
        for (int ni = 0; ni < 4; ++ni)
          acc[mi][ni] = __builtin_amdgcn_mfma_f32_16x16x32_f16(a[mi], bfr[ni], acc[mi][ni], 0, 0, 0);
    }

    #pragma unroll
    for (int ni = 0; ni < 4; ++ni) {
      const int g = ng * 256 + (w * 4 + ni) * 16 + (lane & 15);
      const float bias = b_ih[g] + b_hh[g];
      const int colw = (w * 4 + ni) * 16 + (lane & 15);
      #pragma unroll
      for (int mi = 0; mi < 4; ++mi)
        #pragma unroll
        for (int r = 0; r < 4; ++r)
          s_out[(mi * 16 + (lane >> 4) * 4 + r) * 264 + colw] = (_Float16)(acc[mi][ni][r] + bias);
    }
    __syncthreads();

    #pragma unroll
    for (int i = 0; i < 8; ++i) {
      const int cid = i * 256 + tid;             // 2048 chunks of 8 halfs
      const int row = cid >> 5;
      const int c8  = (cid & 31) * 8;
      const half8 v = *(const half8*)&s_out[row * 264 + c8];
      const int phi = ((c8 >> 7) & 1) * 512 + ng * 128 + (c8 & 127);
      *(half8*)(g_gx + (size_t)(m0 + row) * GATES + phi) = v;
    }
    __syncthreads();
  }
}

// ---- recurrent: 63 clusters x 2 blocks x 5 waves --------------------------
// WAVE SPECIALIZATION: waves 0-3 compute (unchanged roles: wave w owns all 4
// gate types for its 32 dims; wave-local cell update). Wave 4 = POLLER: it
// alone spins on the peer's g_hx publishes (its own vmcnt; tight re-poll)
// and hands A-fragments to compute waves through LDS (release/acquire flag).
// Compute waves' wait is an LDS-flag probe (~40cy) instead of a 500-900cy
// global RTT, and their vmcnt is never drained per step (publish stores and
// y atomics stay fire-and-forget). The poller starts polling region t+1
// right after handing off t, so the cold-line miss is absorbed during step
// t's compute. Per-step sync among the 4 compute waves is an LDS
// sense-counter barrier (s_barrier would block on the free-running poller).
// Slot-reuse guard: poller writes region r (slot r&1) only after
// s_bar >= 4*(r-1), i.e. all compute waves consumed region r-2. Deadlock-
// free: regions 0/1 are unguarded and region 0 is pre-zeroed (h_0 = 0).
__global__ __launch_bounds__(320, 1) void rec_kernel(
    const float* __restrict__ W_out, const float* __restrict__ b_out,
    float* __restrict__ y) {
  __shared__ float s_g[4 * 16 * 132];  // per-wave gate regions (pad 132)
  __shared__ half8 s_h[2][256];        // own-half h, A-order, dbl-buffered
  __shared__ u64   s_ph[2][4][64][2];  // peer-half frags [slot][kk][lane][plane]
  __shared__ int   s_rdy;              // highest region handed off by poller
  __shared__ int   s_bar;              // monotone step-barrier counter

  const int tid = threadIdx.x;
  const int l   = tid & 63;
  const int w   = tid >> 6;            // 0..3 compute, 4 = poller
  const int c   = blockIdx.x >> 1;     // cluster
  const int b   = blockIdx.x & 1;      // dim-half owner
  const int peer0 = (1 - b) * 4;       // peer's global ks base

  if (tid == 0) { s_rdy = -1; s_bar = 0; }
  if (tid < 256) {                     // zero s_h buffer 0 (h_0 = 0)
    ((u64*)&s_h[0][0])[tid]       = 0ull;
    ((u64*)&s_h[0][0])[256 + tid] = 0ull;
  }
  __syncthreads();                     // all 5 waves; only barrier in kernel

  if (w == 4) {
    // ------------------------- poller wave --------------------------------
    for (int r = 0; r < NT; ++r) {
      if (r >= 2) {                    // slot-reuse guard
        while (__hip_atomic_load(&s_bar, __ATOMIC_ACQUIRE,
                                 __HIP_MEMORY_SCOPE_WORKGROUP) < 4 * (r - 1)) {}
      }
      const u64* hsrc = g_hx + ((size_t)r * NCL + c) * 1024;
      u64 pv[8];
      #pragma unroll
      for (int kk = 0; kk < 4; ++kk) {
        pv[2 * kk]     = __hip_atomic_load(hsrc +       (peer0 + kk) * 64 + l,
                                           __ATOMIC_RELAXED, __HIP_MEMORY_SCOPE_AGENT);
        pv[2 * kk + 1] = __hip_atomic_load(hsrc + 512 + (peer0 + kk) * 64 + l,
                                           __ATOMIC_RELAXED, __HIP_MEMORY_SCOPE_AGENT);
      }
      bool pending = false;
      #pragma unroll
      for (int k = 0; k < 8; ++k) pending |= (pv[k] == SENT);
      int tries = 0;
      while (pending && ++tries < (1 << 20)) {
        pending = false;
        #pragma unroll
        for (int kk = 0; kk < 4; ++kk) {
          if (pv[2 * kk] == SENT)
            pv[2 * kk] = __hip_atomic_load(hsrc + (peer0 + kk) * 64 + l,
                                           __ATOMIC_RELAXED, __HIP_MEMORY_SCOPE_AGENT);
          if (pv[2 * kk + 1] == SENT)
            pv[2 * kk + 1] = __hip_atomic_load(hsrc + 512 + (peer0 + kk) * 64 + l,
                                               __ATOMIC_RELAXED, __HIP_MEMORY_SCOPE_AGENT);
        }
        #pragma unroll
        for (int k = 0; k < 8; ++k) pending |= (pv[k] == SENT);
      }
      const int slot = r & 1;
      #pragma unroll
      for (int kk = 0; kk < 4; ++kk)   // ds_write_b128 x4
        *(u64x2*)&s_ph[slot][kk][l][0] = (u64x2){pv[2 * kk], pv[2 * kk + 1]};
      // release: data writes ordered before the flag
      __hip_atomic_store(&s_rdy, r, __ATOMIC_RELEASE, __HIP_MEMORY_SCOPE_WORKGROUP);
    }
    return;
  }

  // --------------------------- compute waves ------------------------------
  // one-time: W_hh slice -> registers (all reg indices compile-time const).
  half8 wf[8][8];
  #pragma unroll
  for (int slot = 0; slot < 8; ++slot) {
    const int lt = (slot >> 1) * 8 + 2 * w + (slot & 1);
    #pragma unroll
    for (int kk = 0; kk < 4; ++kk) {
      wf[slot][kk] = *(const half8*)(g_whf +
          ((size_t)((b * 32 + lt) * 8 + (b * 4 + kk)) * 64 + l) * 8);
      wf[slot][4 + kk] = *(const half8*)(g_whf +
          ((size_t)((b * 32 + lt) * 8 + ((1 - b) * 4 + kk)) * 64 + l) * 8);
    }
  }

  const int pt  = l & 15;
  const int jg  = l >> 4;
  float cs[8];
  float wo[8];
  #pragma unroll
  for (int j = 0; j < 8; ++j) {
    cs[j] = 0.f;
    wo[j] = W_out[b * 128 + 32 * w + jg * 8 + j];
  }
  const float bo_eff = (b == 0 && w == 0) ? b_out[0] : 0.f;
  const int n_pt  = c * CPTS + pt;
  const int rn_pt = (n_pt < NGRID) ? n_pt : (NGRID - 1);

  for (int t = 0; t < NT; ++t) {
    const int cur = t & 1, nxt = cur ^ 1;

    // 1) gx loads straight into the consuming lane's registers (non-temporal)
    half8 gxr[4];
    {
      const _Float16* gsrc = g_gx + ((size_t)t * NGRID + rn_pt) * GATES
                           + b * 512 + 32 * w + jg * 8;
      #pragma unroll
      for (int off = 0; off < 4; ++off)
        gxr[off] = __builtin_nontemporal_load((const half8*)(gsrc + off * 128));
    }

    floatx4 acc[8];
    #pragma unroll
    for (int i = 0; i < 8; ++i) acc[i] = (floatx4){0.f, 0.f, 0.f, 0.f};

    // 2) own-half MFMAs from LDS (overlaps poller's detection of region t)
    #pragma unroll
    for (int kk = 0; kk < 4; ++kk) {
      const half8 af = s_h[cur][kk * 64 + l];
      #pragma unroll
      for (int i = 0; i < 8; ++i)
        acc[i] = __builtin_amdgcn_mfma_f32_16x16x32_f16(af, wf[i][kk], acc[i], 0, 0, 0);
    }

    // 3) wait for poller handoff of region t (LDS flag, acquire)
    while (__hip_atomic_load(&s_rdy, __ATOMIC_ACQUIRE,
                             __HIP_MEMORY_SCOPE_WORKGROUP) < t) {}

    // 4) peer-half MFMAs from s_ph
    #pragma unroll
    for (int kk = 0; kk < 4; ++kk) {
      union { u64x2 v; half8 h; } af;
      af.v = *(const u64x2*)&s_ph[t & 1][kk][l][0];
      #pragma unroll
      for (int i = 0; i < 8; ++i)
        acc[i] = __builtin_amdgcn_mfma_f32_16x16x32_f16(af.h, wf[i][4 + kk], acc[i], 0, 0, 0);
    }

    // 5) scatter acc -> wave-local s_g region (no barrier: same-wave reuse)
    #pragma unroll
    for (int slot = 0; slot < 8; ++slot) {
      const int colw = (slot >> 1) * 32 + (slot & 1) * 16 + pt;
      #pragma unroll
      for (int r = 0; r < 4; ++r)
        s_g[w * 2112 + (jg * 4 + r) * 132 + colw] = acc[slot][r];
    }

    // 6) cell update for this lane's 8 dims (wave-local gates; lgkm only)
    {
      const float* gp = &s_g[w * 2112 + pt * 132 + jg * 8];
      union { u64 u[2]; half8 h8; _Float16 h[8]; } pub;
      float yp = 0.f;
      #pragma unroll
      for (int j = 0; j < 8; ++j) {
        const float gi = gp[j]      + (float)gxr[0][j];
        const float gf = gp[32 + j] + (float)gxr[1][j];
        const float gg = gp[64 + j] + (float)gxr[2][j];
        const float go = gp[96 + j] + (float)gxr[3][j];
        const float i_ = fsig(gi);
        const float f_ = fsig(gf);
        const float g_ = ftanh(gg);
        const float o_ = fsig(go);
        cs[j] = f_ * cs[j] + i_ * g_;
        const float h = o_ * ftanh(cs[j]);
        pub.h[j] = (_Float16)h;
        yp += wo[j] * h;
      }
      // 7) publish wave's ks slice (2 coalesced 512B stores) + own-half LDS
      if (t < NT - 1) {
        u64* dst = g_hx + ((size_t)(t + 1) * NCL + c) * 1024 + (b * 4 + w) * 64 + l;
        __hip_atomic_store(dst,       pub.u[0], __ATOMIC_RELAXED, __HIP_MEMORY_SCOPE_AGENT);
        __hip_atomic_store(dst + 512, pub.u[1], __ATOMIC_RELAXED, __HIP_MEMORY_SCOPE_AGENT);
      }
      s_h[nxt][w * 64 + l] = pub.h8;
      // 8) y: reduce partial over the 4 jg-lanes of this pt, then atomicAdd
      //    (fire-and-forget: never vmcnt-drained)
      yp += __shfl_xor(yp, 16);
      yp += __shfl_xor(yp, 32);
      if (jg == 0 && n_pt < NGRID)
        atomicAdd(&y[(size_t)t * NGRID + n_pt], yp + bo_eff);
    }

    // 9) LDS sense-counter barrier among the 4 compute waves: s_h(t+1)
    //    visible; also signals the poller's slot-reuse guard.
    if (t < NT - 1) {
      if (l == 0)
        __hip_atomic_fetch_add(&s_bar, 1, __ATOMIC_RELEASE,
                               __HIP_MEMORY_SCOPE_WORKGROUP);
      const int target = 4 * (t + 1);
      while (__hip_atomic_load(&s_bar, __ATOMIC_ACQUIRE,
                               __HIP_MEMORY_SCOPE_WORKGROUP) < target) {}
    }
  }
}

extern "C" void kernel_launch(void* const* d_in, const int* in_sizes, int n_in,
                              void* d_out, int out_size, void* d_ws, size_t ws_size,
                              hipStream_t stream) {
  (void)in_sizes; (void)n_in; (void)out_size; (void)d_ws; (void)ws_size;
  const float* x     = (const float*)d_in[0];
  // d_in[1] = wt_ih (zeros in eval mode, unused)
  const float* W_in  = (const float*)d_in[2];
  const float* b_in  = (const float*)d_in[3];
  const float* W_ih  = (const float*)d_in[4];
  const float* W_hh  = (const float*)d_in[5];
  const float* b_ih  = (const float*)d_in[6];
  const float* b_hh  = (const float*)d_in[7];
  const float* W_out = (const float*)d_in[8];
  const float* b_out = (const float*)d_in[9];
  float* y           = (float*)d_out;

  hipLaunchKernelGGL(pack_wf_kernel, dim3(256), dim3(256), 0, stream, W_ih, W_hh);
  hipLaunchKernelGGL(gx_kernel, dim3(MBLK), dim3(256), 0, stream,
                     x, W_in, b_in, b_ih, b_hh, y);
  hipLaunchKernelGGL(rec_kernel, dim3(NCL * 2), dim3(320), 0, stream, W_out, b_out, y);
}

// Round 3
// 2845.054 us; speedup vs baseline: 1.1050x; 1.1050x over previous
//
#include <hip/hip_runtime.h>
#include <hip/hip_fp16.h>

#define NT    365
#define NGRID 1000
#define NXI   20
#define HID   256
#define GATES 1024
#define MROWS 365000          // NT*NGRID
#define MBLK  5704            // ceil(MROWS/64)
#define MPAD  (MBLK * 64)
#define NCL   63              // clusters (16 pts each, last ragged)
#define CPTS  16
// 2-slot ring for h exchange: slot = t&1. 63*2*1024 u64 = 1.008 MB -> stays
// IF$-hot forever (vs the old 188MB deep buffer whose lines were always
// HBM-cold at poll time). WAR safety: consumer restores SENT after spin
// (post-spin barrier first), producer's wave0 publish is RELEASE.
#define HX_RING ((size_t)2 * NCL * 1024)
#define HX_ZERO ((size_t)NCL * 1024)       // slot 0 = region 0 = h_0 = zeros

typedef _Float16 half8 __attribute__((ext_vector_type(8)));
typedef float floatx4 __attribute__((ext_vector_type(4)));
typedef unsigned long long u64;

#define SENT 0xFFFFFFFFFFFFFFFFull   // 4x fp16 -NaN: unreachable (|h|<=1)

// Module-scope globals (d_ws too small). Fully rewritten/reset every launch.
__device__ _Float16 g_gx[(size_t)MPAD * GATES];   // gx, block-local column layout
__device__ _Float16 g_wif[64 * 8 * 512];          // W_ih B-frags (global n-tiles)
__device__ _Float16 g_whf[2 * 32 * 8 * 64 * 8];   // W_hh B-frags, split by rec block
// h exchange ring, A-FRAGMENT ORDER, plane-split: chunk[(ks)*64 + lane]
// (+512 for the 2nd u64 of the half8). Sentinel protocol.
__device__ u64 g_hx[HX_RING];

__device__ __forceinline__ float fsig(float x) {
  return __fdividef(1.f, 1.f + __expf(-x));
}
__device__ __forceinline__ float ftanh(float x) {
  return 1.f - __fdividef(2.f, __expf(2.f * x) + 1.f);
}

// ---- pack weights into MFMA B-fragment layouts + ring init ----------------
// B-frag 16x16x32: lane holds B[n=tile*16+(lane&15)][k=ks*32+(lane>>4)*8+j]
__global__ __launch_bounds__(256) void pack_wf_kernel(
    const float* __restrict__ W_ih, const float* __restrict__ W_hh) {
  const int gid = blockIdx.x * 256 + threadIdx.x;   // 0..65535
  // ring init: slot0 = zeros (h_0), slot1 = SENT. 129024 u64 total.
  {
    const size_t j0 = (size_t)gid * 2;
    if (j0 < HX_RING)     g_hx[j0]     = (j0 < HX_ZERO)     ? 0ull : SENT;
    if (j0 + 1 < HX_RING) g_hx[j0 + 1] = (j0 + 1 < HX_ZERO) ? 0ull : SENT;
  }
  const float* src;
  _Float16* dst;
  int n, k0, lane;
  if (gid < 32768) {                 // W_ih -> g_wif, global n-tile layout
    const int tile = gid >> 9;
    const int ks   = (gid >> 6) & 7;
    lane = gid & 63;
    n  = tile * 16 + (lane & 15);
    k0 = ks * 32 + (lane >> 4) * 8;
    src = W_ih + n * HID + k0;
    dst = g_wif + ((size_t)(tile * 8 + ks) * 64 + lane) * 8;
  } else {                           // W_hh -> g_whf, [b][ltile][ks global]
    const int rem = gid - 32768;
    const int b2  = rem >> 14;       // owning rec block (dim half)
    const int lt  = (rem >> 9) & 31; // local tile = tau*8 + sub
    const int ks  = (rem >> 6) & 7;
    lane = rem & 63;
    const int nt = (lt >> 3) * 16 + b2 * 8 + (lt & 7);
    n  = nt * 16 + (lane & 15);
    k0 = ks * 32 + (lane >> 4) * 8;
    src = W_hh + n * HID + k0;
    dst = g_whf + ((size_t)((b2 * 32 + lt) * 8 + ks) * 64 + lane) * 8;
  }
  const float4 a = *(const float4*)(src);
  const float4 b = *(const float4*)(src + 4);
  half8 h;
  h[0] = (_Float16)a.x; h[1] = (_Float16)a.y; h[2] = (_Float16)a.z; h[3] = (_Float16)a.w;
  h[4] = (_Float16)b.x; h[5] = (_Float16)b.y; h[6] = (_Float16)b.z; h[7] = (_Float16)b.w;
  *(half8*)dst = h;
}

// ---- gx = relu(x@W_in.T+b_in) @ W_ih.T + (b_ih+b_hh), fused ---------------
// Output column layout per row: phi(g) = b*512 + tau*128 + (g&127).
__global__ __launch_bounds__(256, 2) void gx_kernel(
    const float* __restrict__ x, const float* __restrict__ W_in,
    const float* __restrict__ b_in, const float* __restrict__ b_ih,
    const float* __restrict__ b_hh, float* __restrict__ y) {
  {
    const size_t gid = (size_t)blockIdx.x * 256 + threadIdx.x;
    if (gid < MROWS) y[gid] = 0.f;
  }

  __shared__ float s_x[64 * NXI];
  __shared__ _Float16 s_x0[64 * 264];
  __shared__ _Float16 s_out[64 * 264];

  const int tid  = threadIdx.x;
  const int lane = tid & 63;
  const int w    = tid >> 6;
  const int m0   = blockIdx.x * 64;

  #pragma unroll
  for (int i = 0; i < 5; ++i) {
    const int idx = i * 256 + tid;
    size_t g = (size_t)m0 * NXI + idx;
    const size_t gmax = (size_t)MROWS * NXI - 1;
    if (g > gmax) g = gmax;
    s_x[idx] = x[g];
  }
  float wv[NXI];
  #pragma unroll
  for (int k = 0; k < NXI; ++k) wv[k] = W_in[tid * NXI + k];
  const float bv = b_in[tid];
  __syncthreads();

  for (int r = 0; r < 64; ++r) {
    float acc = bv;
    #pragma unroll
    for (int qq = 0; qq < 5; ++qq) {
      const float4 xa = *(const float4*)&s_x[r * NXI + qq * 4];
      acc += xa.x * wv[qq * 4 + 0] + xa.y * wv[qq * 4 + 1] +
             xa.z * wv[qq * 4 + 2] + xa.w * wv[qq * 4 + 3];
    }
    s_x0[r * 264 + tid] = (_Float16)fmaxf(acc, 0.f);
  }
  __syncthreads();

  for (int ng = 0; ng < 4; ++ng) {    // 4 groups of 256 gates
    floatx4 acc[4][4];
    #pragma unroll
    for (int mi = 0; mi < 4; ++mi)
      #pragma unroll
      for (int ni = 0; ni < 4; ++ni) acc[mi][ni] = (floatx4){0.f, 0.f, 0.f, 0.f};

    #pragma unroll
    for (int ks = 0; ks < 8; ++ks) {
      half8 a[4], bfr[4];
      #pragma unroll
      for (int mi = 0; mi < 4; ++mi)
        a[mi] = *(const half8*)&s_x0[(mi * 16 + (lane & 15)) * 264 + ks * 32 + (lane >> 4) * 8];
      #pragma unroll
      for (int ni = 0; ni < 4; ++ni) {
        const int nt = ng * 16 + w * 4 + ni;
        bfr[ni] = *(const half8*)(g_wif + ((size_t)(nt * 8 + ks) * 64 + lane) * 8);
      }
      #pragma unroll
      for (int mi = 0; mi < 4; ++mi)
        #pragma unroll
        for (int ni = 0; ni < 4; ++ni)
          acc[mi][ni] = __builtin_amdgcn_mfma_f32_16x16x32_f16(a[mi], bfr[ni], acc[mi][ni], 0, 0, 0);
    }

    #pragma unroll
    for (int ni = 0; ni < 4; ++ni) {
      const int g = ng * 256 + (w * 4 + ni) * 16 + (lane & 15);
      const float bias = b_ih[g] + b_hh[g];
      const int colw = (w * 4 + ni) * 16 + (lane & 15);
      #pragma unroll
      for (int mi = 0; mi < 4; ++mi)
        #pragma unroll
        for (int r = 0; r < 4; ++r)
          s_out[(mi * 16 + (lane >> 4) * 4 + r) * 264 + colw] = (_Float16)(acc[mi][ni][r] + bias);
    }
    __syncthreads();

    #pragma unroll
    for (int i = 0; i < 8; ++i) {
      const int cid = i * 256 + tid;             // 2048 chunks of 8 halfs
      const int row = cid >> 5;
      const int c8  = (cid & 31) * 8;
      const half8 v = *(const half8*)&s_out[row * 264 + c8];
      const int phi = ((c8 >> 7) & 1) * 512 + ng * 128 + (c8 & 127);
      *(half8*)(g_gx + (size_t)(m0 + row) * GATES + phi) = v;
    }
    __syncthreads();
  }
}

// ---- recurrent: 63 clusters x 2 blocks; wave-autonomous gate slices -------
// R0 structure restored (256 thr, wf[8][8] in AGPRs, batched spin on the
// compute waves). New: 2-slot IF$-hot ring for the h exchange.
// Protocol per step t (slot s = t&1):
//   spin on peer half of slot s (relaxed, batched re-poll)
//   s_barrier                      <- all 4 waves done READING slot s
//   wave0: restore SENT to the 8 polled u64 (relaxed)
//   ... peer MFMAs, cell update ...
//   publish own half of slot s^1: wave0's first store RELEASE (orders the
//     restores before it; peer's poll-completion requires wave0's chunk,
//     so restores are visible before peer can publish t+2 into slot s),
//     waves 1-3 fully relaxed (their vmcnt never drains).
//   y atomicAdd AFTER publish (keeps it out of wave0's release drain)
//   lgkm-only barrier for s_h double-buffer.
__global__ __launch_bounds__(256, 1) void rec_kernel(
    const float* __restrict__ W_out, const float* __restrict__ b_out,
    float* __restrict__ y) {
  __shared__ float s_g[4 * 16 * 132];  // per-wave gate regions (pad 132)
  __shared__ half8 s_h[2][256];        // own-half h, A-order, dbl-buffered

  const int tid = threadIdx.x;
  const int l   = tid & 63;
  const int w   = tid >> 6;
  const int c   = blockIdx.x >> 1;     // cluster
  const int b   = blockIdx.x & 1;      // dim-half owner
  const int pt  = l & 15;
  const int jg  = l >> 4;

  // one-time: W_hh slice -> registers (AGPR-resident; all reg indices are
  // compile-time constants; runtime w/b only in ADDRESSES).
  half8 wf[8][8];
  #pragma unroll
  for (int slot = 0; slot < 8; ++slot) {
    const int lt = (slot >> 1) * 8 + 2 * w + (slot & 1);
    #pragma unroll
    for (int kk = 0; kk < 4; ++kk) {
      wf[slot][kk] = *(const half8*)(g_whf +
          ((size_t)((b * 32 + lt) * 8 + (b * 4 + kk)) * 64 + l) * 8);
      wf[slot][4 + kk] = *(const half8*)(g_whf +
          ((size_t)((b * 32 + lt) * 8 + ((1 - b) * 4 + kk)) * 64 + l) * 8);
    }
  }

  float cs[8];
  float wo[8];
  #pragma unroll
  for (int j = 0; j < 8; ++j) {
    cs[j] = 0.f;
    wo[j] = W_out[b * 128 + 32 * w + jg * 8 + j];
  }
  const float bo_eff = (b == 0 && w == 0) ? b_out[0] : 0.f;
  const int n_pt  = c * CPTS + pt;
  const int rn_pt = (n_pt < NGRID) ? n_pt : (NGRID - 1);
  const int peer0 = (1 - b) * 4;       // peer's global ks base

  // zero s_h buffer 0 (h_0 = 0)
  ((u64*)&s_h[0][0])[tid]       = 0ull;
  ((u64*)&s_h[0][0])[256 + tid] = 0ull;
  __syncthreads();

  for (int t = 0; t < NT; ++t) {
    const int cur = t & 1, nxt = cur ^ 1;
    const bool hasnext = (t + 1 < NT);
    u64* hsrc = g_hx + ((size_t)(t & 1) * NCL + c) * 1024;

    // 1) gx loads straight into the consuming lane's registers (non-temporal:
    //    keep the 747MB stream from evicting the hot ring lines)
    half8 gxr[4];
    {
      const _Float16* gsrc = g_gx + ((size_t)t * NGRID + rn_pt) * GATES
                           + b * 512 + 32 * w + jg * 8;
      #pragma unroll
      for (int off = 0; off < 4; ++off)
        gxr[off] = __builtin_nontemporal_load((const half8*)(gsrc + off * 128));
    }

    // 2) issue peer poll loads (coalesced: 8B lane stride per chunk-slice)
    u64 pv[8];
    #pragma unroll
    for (int kk = 0; kk < 4; ++kk) {
      pv[2 * kk]     = __hip_atomic_load(hsrc +       (peer0 + kk) * 64 + l,
                                         __ATOMIC_RELAXED, __HIP_MEMORY_SCOPE_AGENT);
      pv[2 * kk + 1] = __hip_atomic_load(hsrc + 512 + (peer0 + kk) * 64 + l,
                                         __ATOMIC_RELAXED, __HIP_MEMORY_SCOPE_AGENT);
    }

    floatx4 acc[8];
    #pragma unroll
    for (int i = 0; i < 8; ++i) acc[i] = (floatx4){0.f, 0.f, 0.f, 0.f};

    // 3) own-half MFMAs from LDS while peer loads are in flight
    #pragma unroll
    for (int kk = 0; kk < 4; ++kk) {
      const half8 af = s_h[cur][kk * 64 + l];
      #pragma unroll
      for (int i = 0; i < 8; ++i)
        acc[i] = __builtin_amdgcn_mfma_f32_16x16x32_f16(af, wf[i][kk], acc[i], 0, 0, 0);
    }

    // 4) BATCHED spin: re-issue all pending chunks each iteration (~1 RTT).
    //    Ring lines are IF$-hot (1MB working set, touched every step).
    {
      bool pending = false;
      #pragma unroll
      for (int k = 0; k < 8; ++k) pending |= (pv[k] == SENT);
      int tries = 0;
      while (pending && ++tries < (1 << 18)) {
        pending = false;
        #pragma unroll
        for (int kk = 0; kk < 4; ++kk) {
          if (pv[2 * kk] == SENT)
            pv[2 * kk] = __hip_atomic_load(hsrc + (peer0 + kk) * 64 + l,
                                           __ATOMIC_RELAXED, __HIP_MEMORY_SCOPE_AGENT);
          if (pv[2 * kk + 1] == SENT)
            pv[2 * kk + 1] = __hip_atomic_load(hsrc + 512 + (peer0 + kk) * 64 + l,
                                               __ATOMIC_RELAXED, __HIP_MEMORY_SCOPE_AGENT);
        }
        #pragma unroll
        for (int k = 0; k < 8; ++k) pending |= (pv[k] == SENT);
      }
    }

    // 4b) all 4 waves are past READING slot t&1 -> wave0 may restore SENT
    __builtin_amdgcn_s_barrier();
    if (w == 0 && hasnext) {
      #pragma unroll
      for (int kk = 0; kk < 4; ++kk) {
        __hip_atomic_store(hsrc +       (peer0 + kk) * 64 + l, SENT,
                           __ATOMIC_RELAXED, __HIP_MEMORY_SCOPE_AGENT);
        __hip_atomic_store(hsrc + 512 + (peer0 + kk) * 64 + l, SENT,
                           __ATOMIC_RELAXED, __HIP_MEMORY_SCOPE_AGENT);
      }
    }

    // 5) peer-half MFMAs
    #pragma unroll
    for (int kk = 0; kk < 4; ++kk) {
      union { u64 u[2]; half8 h; } af;
      af.u[0] = pv[2 * kk];
      af.u[1] = pv[2 * kk + 1];
      #pragma unroll
      for (int i = 0; i < 8; ++i)
        acc[i] = __builtin_amdgcn_mfma_f32_16x16x32_f16(af.h, wf[i][4 + kk], acc[i], 0, 0, 0);
    }

    // 6) scatter acc -> wave-local s_g region (no barrier: same-wave reuse)
    #pragma unroll
    for (int slot = 0; slot < 8; ++slot) {
      const int colw = (slot >> 1) * 32 + (slot & 1) * 16 + pt; // pt = lane&15
      #pragma unroll
      for (int r = 0; r < 4; ++r)
        s_g[w * 2112 + (jg * 4 + r) * 132 + colw] = acc[slot][r];
    }

    // 7) cell update for this lane's 8 dims (wave-local gates; lgkm only)
    {
      const float* gp = &s_g[w * 2112 + pt * 132 + jg * 8];
      union { u64 u[2]; half8 h8; _Float16 h[8]; } pub;
      float yp = 0.f;
      #pragma unroll
      for (int j = 0; j < 8; ++j) {
        const float gi = gp[j]      + (float)gxr[0][j];
        const float gf = gp[32 + j] + (float)gxr[1][j];
        const float gg = gp[64 + j] + (float)gxr[2][j];
        const float go = gp[96 + j] + (float)gxr[3][j];
        const float i_ = fsig(gi);
        const float f_ = fsig(gf);
        const float g_ = ftanh(gg);
        const float o_ = fsig(go);
        cs[j] = f_ * cs[j] + i_ * g_;
        const float h = o_ * ftanh(cs[j]);
        pub.h[j] = (_Float16)h;
        yp += wo[j] * h;
      }
      // 8) publish wave's ks slice to slot (t+1)&1. wave0's first store is
      //    RELEASE (orders the SENT-restores before it); everything else
      //    relaxed -> waves 1-3 never drain vmcnt.
      if (hasnext) {
        u64* dst = g_hx + ((size_t)((t + 1) & 1) * NCL + c) * 1024
                 + (b * 4 + w) * 64 + l;
        if (w == 0)
          __hip_atomic_store(dst, pub.u[0], __ATOMIC_RELEASE, __HIP_MEMORY_SCOPE_AGENT);
        else
          __hip_atomic_store(dst, pub.u[0], __ATOMIC_RELAXED, __HIP_MEMORY_SCOPE_AGENT);
        __hip_atomic_store(dst + 512, pub.u[1], __ATOMIC_RELAXED, __HIP_MEMORY_SCOPE_AGENT);
      }
      s_h[nxt][w * 64 + l] = pub.h8;
      // 9) y: reduce partial over the 4 jg-lanes of this pt, then atomicAdd
      //    (after publish: stays out of wave0's release drain)
      yp += __shfl_xor(yp, 16);
      yp += __shfl_xor(yp, 32);
      if (jg == 0 && n_pt < NGRID)
        atomicAdd(&y[(size_t)t * NGRID + n_pt], yp + bo_eff);
    }

    // 10) lgkm-only barrier: s_h(t+1) complete across waves; publishes and
    //     y-atomics stay in flight (no vmcnt drain).
    asm volatile("s_waitcnt lgkmcnt(0)" ::: "memory");
    __builtin_amdgcn_s_barrier();
  }
}

extern "C" void kernel_launch(void* const* d_in, const int* in_sizes, int n_in,
                              void* d_out, int out_size, void* d_ws, size_t ws_size,
                              hipStream_t stream) {
  (void)in_sizes; (void)n_in; (void)out_size; (void)d_ws; (void)ws_size;
  const float* x     = (const float*)d_in[0];
  // d_in[1] = wt_ih (zeros in eval mode, unused)
  const float* W_in  = (const float*)d_in[2];
  const float* b_in  = (const float*)d_in[3];
  const float* W_ih  = (const float*)d_in[4];
  const float* W_hh  = (const float*)d_in[5];
  const float* b_ih  = (const float*)d_in[6];
  const float* b_hh  = (const float*)d_in[7];
  const float* W_out = (const float*)d_in[8];
  const float* b_out = (const float*)d_in[9];
  float* y           = (float*)d_out;

  hipLaunchKernelGGL(pack_wf_kernel, dim3(256), dim3(256), 0, stream, W_ih, W_hh);
  hipLaunchKernelGGL(gx_kernel, dim3(MBLK), dim3(256), 0, stream,
                     x, W_in, b_in, b_ih, b_hh, y);
  hipLaunchKernelGGL(rec_kernel, dim3(NCL * 2), dim3(256), 0, stream, W_out, b_out, y);
}

// Round 4
// 1924.351 us; speedup vs baseline: 1.6336x; 1.4784x over previous
//
#include <hip/hip_runtime.h>
#include <hip/hip_fp16.h>

#define NT    365
#define NGRID 1000
#define NXI   20
#define HID   256
#define GATES 1024
#define MROWS 365000          // NT*NGRID
#define MBLK  5704            // ceil(MROWS/64)
#define MPAD  (MBLK * 64)
#define NCL   63              // clusters (16 pts each, last ragged)
#define CPTS  16
#define HX_TOT ((size_t)NT * NCL * 1024)   // u64 slots, deep buffer (188MB)
#define HX_ZERO ((size_t)NCL * 1024)       // t=0 region: zeros (h_0 = 0)
#define YX_TOT ((size_t)NT * NCL * 16)     // y-partial channel (deep, 2.9MB)

typedef _Float16 half8 __attribute__((ext_vector_type(8)));
typedef float floatx4 __attribute__((ext_vector_type(4)));
typedef unsigned long long u64;

#define SENT 0xFFFFFFFFFFFFFFFFull   // 4x fp16 -NaN: unreachable (|h|<=1)

// Module-scope globals (d_ws too small). Fully rewritten/reset every launch.
__device__ _Float16 g_gx[(size_t)MPAD * GATES];   // gx, block-local column layout
__device__ _Float16 g_wif[64 * 8 * 512];          // W_ih B-frags (global n-tiles)
__device__ _Float16 g_whf[2 * 32 * 8 * 64 * 8];   // W_hh B-frags, split by rec block
// h exchange, A-FRAGMENT ORDER, plane-split: chunk[(ks)*64 + lane] (+512 for
// the 2nd u64 of the half8). Sentinel protocol; deep t-indexed buffer.
__device__ u64 g_hx[HX_TOT];
// y-partial exchange: block b=1 publishes its folded 16 partials per step;
// block b=0 consumes 2 steps delayed (guaranteed-published by h lockstep)
// and writes y with a PLAIN store. Replaces 128 contended atomicAdd RMWs
// per cluster-step (the per-step vmcnt drain was waiting on their acks).
__device__ u64 g_yx[YX_TOT];

__device__ __forceinline__ float fsig(float x) {
  return __fdividef(1.f, 1.f + __expf(-x));
}
__device__ __forceinline__ float ftanh(float x) {
  return 1.f - __fdividef(2.f, __expf(2.f * x) + 1.f);
}

// ---- init: zero g_hx[t=0], sentinel-fill the rest + y-channel -------------
__global__ __launch_bounds__(256) void init_kernel() {
  const size_t i = (size_t)blockIdx.x * 256 + threadIdx.x;
  const size_t j = i * 2;
  if (j < HX_TOT)     g_hx[j]     = (j < HX_ZERO)     ? 0ull : SENT;
  if (j + 1 < HX_TOT) g_hx[j + 1] = (j + 1 < HX_ZERO) ? 0ull : SENT;
  if (i < YX_TOT) g_yx[i] = SENT;
}

// ---- pack weights into MFMA B-fragment layouts ----------------------------
// B-frag 16x16x32: lane holds B[n=tile*16+(lane&15)][k=ks*32+(lane>>4)*8+j]
__global__ __launch_bounds__(256) void pack_wf_kernel(
    const float* __restrict__ W_ih, const float* __restrict__ W_hh) {
  const int gid = blockIdx.x * 256 + threadIdx.x;   // 0..65535
  const float* src;
  _Float16* dst;
  int n, k0, lane;
  if (gid < 32768) {                 // W_ih -> g_wif, global n-tile layout
    const int tile = gid >> 9;
    const int ks   = (gid >> 6) & 7;
    lane = gid & 63;
    n  = tile * 16 + (lane & 15);
    k0 = ks * 32 + (lane >> 4) * 8;
    src = W_ih + n * HID + k0;
    dst = g_wif + ((size_t)(tile * 8 + ks) * 64 + lane) * 8;
  } else {                           // W_hh -> g_whf, [b][ltile][ks global]
    const int rem = gid - 32768;
    const int b2  = rem >> 14;       // owning rec block (dim half)
    const int lt  = (rem >> 9) & 31; // local tile = tau*8 + sub
    const int ks  = (rem >> 6) & 7;
    lane = rem & 63;
    const int nt = (lt >> 3) * 16 + b2 * 8 + (lt & 7);
    n  = nt * 16 + (lane & 15);
    k0 = ks * 32 + (lane >> 4) * 8;
    src = W_hh + n * HID + k0;
    dst = g_whf + ((size_t)((b2 * 32 + lt) * 8 + ks) * 64 + lane) * 8;
  }
  const float4 a = *(const float4*)(src);
  const float4 b = *(const float4*)(src + 4);
  half8 h;
  h[0] = (_Float16)a.x; h[1] = (_Float16)a.y; h[2] = (_Float16)a.z; h[3] = (_Float16)a.w;
  h[4] = (_Float16)b.x; h[5] = (_Float16)b.y; h[6] = (_Float16)b.z; h[7] = (_Float16)b.w;
  *(half8*)dst = h;
}

// ---- gx = relu(x@W_in.T+b_in) @ W_ih.T + (b_ih+b_hh), fused ---------------
// Output column layout per row: phi(g) = b*512 + tau*128 + (g&127).
__global__ __launch_bounds__(256, 2) void gx_kernel(
    const float* __restrict__ x, const float* __restrict__ W_in,
    const float* __restrict__ b_in, const float* __restrict__ b_ih,
    const float* __restrict__ b_hh) {
  __shared__ float s_x[64 * NXI];
  __shared__ _Float16 s_x0[64 * 264];
  __shared__ _Float16 s_out[64 * 264];

  const int tid  = threadIdx.x;
  const int lane = tid & 63;
  const int w    = tid >> 6;
  const int m0   = blockIdx.x * 64;

  #pragma unroll
  for (int i = 0; i < 5; ++i) {
    const int idx = i * 256 + tid;
    size_t g = (size_t)m0 * NXI + idx;
    const size_t gmax = (size_t)MROWS * NXI - 1;
    if (g > gmax) g = gmax;
    s_x[idx] = x[g];
  }
  float wv[NXI];
  #pragma unroll
  for (int k = 0; k < NXI; ++k) wv[k] = W_in[tid * NXI + k];
  const float bv = b_in[tid];
  __syncthreads();

  for (int r = 0; r < 64; ++r) {
    float acc = bv;
    #pragma unroll
    for (int qq = 0; qq < 5; ++qq) {
      const float4 xa = *(const float4*)&s_x[r * NXI + qq * 4];
      acc += xa.x * wv[qq * 4 + 0] + xa.y * wv[qq * 4 + 1] +
             xa.z * wv[qq * 4 + 2] + xa.w * wv[qq * 4 + 3];
    }
    s_x0[r * 264 + tid] = (_Float16)fmaxf(acc, 0.f);
  }
  __syncthreads();

  for (int ng = 0; ng < 4; ++ng) {    // 4 groups of 256 gates
    floatx4 acc[4][4];
    #pragma unroll
    for (int mi = 0; mi < 4; ++mi)
      #pragma unroll
      for (int ni = 0; ni < 4; ++ni) acc[mi][ni] = (floatx4){0.f, 0.f, 0.f, 0.f};

    #pragma unroll
    for (int ks = 0; ks < 8; ++ks) {
      half8 a[4], bfr[4];
      #pragma unroll
      for (int mi = 0; mi < 4; ++mi)
        a[mi] = *(const half8*)&s_x0[(mi * 16 + (lane & 15)) * 264 + ks * 32 + (lane >> 4) * 8];
      #pragma unroll
      for (int ni = 0; ni < 4; ++ni) {
        const int nt = ng * 16 + w * 4 + ni;
        bfr[ni] = *(const half8*)(g_wif + ((size_t)(nt * 8 + ks) * 64 + lane) * 8);
      }
      #pragma unroll
      for (int mi = 0; mi < 4; ++mi)
        #pragma unroll
        for (int ni = 0; ni < 4; ++ni)
          acc[mi][ni] = __builtin_amdgcn_mfma_f32_16x16x32_f16(a[mi], bfr[ni], acc[mi][ni], 0, 0, 0);
    }

    #pragma unroll
    for (int ni = 0; ni < 4; ++ni) {
      const int g = ng * 256 + (w * 4 + ni) * 16 + (lane & 15);
      const float bias = b_ih[g] + b_hh[g];
      const int colw = (w * 4 + ni) * 16 + (lane & 15);
      #pragma unroll
      for (int mi = 0; mi < 4; ++mi)
        #pragma unroll
        for (int r = 0; r < 4; ++r)
          s_out[(mi * 16 + (lane >> 4) * 4 + r) * 264 + colw] = (_Float16)(acc[mi][ni][r] + bias);
    }
    __syncthreads();

    #pragma unroll
    for (int i = 0; i < 8; ++i) {
      const int cid = i * 256 + tid;             // 2048 chunks of 8 halfs
      const int row = cid >> 5;
      const int c8  = (cid & 31) * 8;
      const half8 v = *(const half8*)&s_out[row * 264 + c8];
      const int phi = ((c8 >> 7) & 1) * 512 + ng * 128 + (c8 & 127);
      *(half8*)(g_gx + (size_t)(m0 + row) * GATES + phi) = v;
    }
    __syncthreads();
  }
}

// ---- recurrent: 63 clusters x 2 blocks; wave-autonomous gate slices -------
// Exact R0 structure (deep g_hx, batched spin, plain __syncthreads step
// barrier). ONE change: y atomicAdds (128 contended RMWs per cluster-step,
// whose acks the barrier drain waited on) are replaced by an LDS fold +
// deep y-partial channel. Block1 publishes its folded partial (relaxed,
// fire-and-forget); block0 consumes it 2 steps delayed (lockstep invariant
// => already published, zero-spin) and writes y with a plain store.
__global__ __launch_bounds__(256, 1) void rec_kernel(
    const float* __restrict__ W_out, const float* __restrict__ b_out,
    float* __restrict__ y) {
  __shared__ float s_g[4 * 16 * 132];  // per-wave gate regions (pad 132)
  __shared__ u64   s_h[2][1024];       // own-half h, A-order, dbl-buffered
  __shared__ float s_y[2][4][16];      // per-wave y partials, dbl-buffered

  const int tid = threadIdx.x;
  const int l   = tid & 63;
  const int w   = tid >> 6;
  const int c   = blockIdx.x >> 1;     // cluster
  const int b   = blockIdx.x & 1;      // dim-half owner
  const int pt  = l & 15;
  const int jg  = l >> 4;

  // one-time: W_hh slice -> registers. slot = off*2+s (all reg indices are
  // compile-time constants; runtime w/b only in ADDRESSES).
  half8 wf[8][8];
  #pragma unroll
  for (int slot = 0; slot < 8; ++slot) {
    const int lt = (slot >> 1) * 8 + 2 * w + (slot & 1);
    #pragma unroll
    for (int kk = 0; kk < 4; ++kk) {
      wf[slot][kk] = *(const half8*)(g_whf +
          ((size_t)((b * 32 + lt) * 8 + (b * 4 + kk)) * 64 + l) * 8);
      wf[slot][4 + kk] = *(const half8*)(g_whf +
          ((size_t)((b * 32 + lt) * 8 + ((1 - b) * 4 + kk)) * 64 + l) * 8);
    }
  }

  float cs[8];
  float wo[8];
  #pragma unroll
  for (int j = 0; j < 8; ++j) {
    cs[j] = 0.f;
    wo[j] = W_out[b * 128 + 32 * w + jg * 8 + j];
  }
  const float bo = b_out[0];
  const int n_pt  = c * CPTS + pt;
  const int rn_pt = (n_pt < NGRID) ? n_pt : (NGRID - 1);
  const int peer0 = (1 - b) * 4;       // peer's global ks base
  const bool ylane = (w == 0) && (jg == 0);
  float yo = 0.f;                      // block0: own folded partial (t-2)

  // zero s_h buffer 0 (h_0 = 0)
  for (int i = tid; i < 1024; i += 256) s_h[0][i] = 0ull;
  __syncthreads();

  for (int t = 0; t < NT; ++t) {
    const int cur = t & 1, nxt = cur ^ 1;

    // 0) y-pipeline head (wave0, lanes 0-15): fold step t-1 partials from
    //    LDS; b==1 publishes, b==0 issues the (t-2) consume load early.
    float own4 = 0.f;
    u64 ypk = 0;
    if (ylane && t >= 1) {
      own4 = s_y[nxt][0][pt] + s_y[nxt][1][pt] +
             s_y[nxt][2][pt] + s_y[nxt][3][pt];
      if (b)
        __hip_atomic_store(&g_yx[((size_t)(t - 1) * NCL + c) * 16 + pt],
                           (u64)__float_as_uint(own4),
                           __ATOMIC_RELAXED, __HIP_MEMORY_SCOPE_AGENT);
    }
    if (ylane && !b && t >= 2)
      ypk = __hip_atomic_load(&g_yx[((size_t)(t - 2) * NCL + c) * 16 + pt],
                              __ATOMIC_RELAXED, __HIP_MEMORY_SCOPE_AGENT);

    // 1) gx loads straight into the consuming lane's registers
    half8 gxr[4];
    {
      const _Float16* gsrc = g_gx + ((size_t)t * NGRID + rn_pt) * GATES
                           + b * 512 + 32 * w + jg * 8;
      #pragma unroll
      for (int off = 0; off < 4; ++off)
        gxr[off] = *(const half8*)(gsrc + off * 128);
    }

    // 2) issue peer poll loads (coalesced: 8B lane stride per chunk-slice)
    const u64* hsrc = g_hx + ((size_t)t * NCL + c) * 1024;
    u64 pv[8];
    #pragma unroll
    for (int kk = 0; kk < 4; ++kk) {
      pv[2 * kk]     = __hip_atomic_load(hsrc +       (peer0 + kk) * 64 + l,
                                         __ATOMIC_RELAXED, __HIP_MEMORY_SCOPE_AGENT);
      pv[2 * kk + 1] = __hip_atomic_load(hsrc + 512 + (peer0 + kk) * 64 + l,
                                         __ATOMIC_RELAXED, __HIP_MEMORY_SCOPE_AGENT);
    }

    floatx4 acc[8];
    #pragma unroll
    for (int i = 0; i < 8; ++i) acc[i] = (floatx4){0.f, 0.f, 0.f, 0.f};

    // 3) own-half MFMAs from LDS while peer loads are in flight
    #pragma unroll
    for (int kk = 0; kk < 4; ++kk) {
      union { u64 u[2]; half8 h; } af;
      af.u[0] = s_h[cur][kk * 64 + l];
      af.u[1] = s_h[cur][512 + kk * 64 + l];
      #pragma unroll
      for (int i = 0; i < 8; ++i)
        acc[i] = __builtin_amdgcn_mfma_f32_16x16x32_f16(af.h, wf[i][kk], acc[i], 0, 0, 0);
    }

    // 4) BATCHED spin: re-issue all pending chunks each iteration (~1 RTT)
    {
      bool pending = false;
      #pragma unroll
      for (int k = 0; k < 8; ++k) pending |= (pv[k] == SENT);
      int tries = 0;
      while (pending && ++tries < (1 << 18)) {
        pending = false;
        #pragma unroll
        for (int kk = 0; kk < 4; ++kk) {
          if (pv[2 * kk] == SENT)
            pv[2 * kk] = __hip_atomic_load(hsrc + (peer0 + kk) * 64 + l,
                                           __ATOMIC_RELAXED, __HIP_MEMORY_SCOPE_AGENT);
          if (pv[2 * kk + 1] == SENT)
            pv[2 * kk + 1] = __hip_atomic_load(hsrc + 512 + (peer0 + kk) * 64 + l,
                                               __ATOMIC_RELAXED, __HIP_MEMORY_SCOPE_AGENT);
        }
        #pragma unroll
        for (int k = 0; k < 8; ++k) pending |= (pv[k] == SENT);
      }
    }

    // 5) peer-half MFMAs
    #pragma unroll
    for (int kk = 0; kk < 4; ++kk) {
      union { u64 u[2]; half8 h; } af;
      af.u[0] = pv[2 * kk];
      af.u[1] = pv[2 * kk + 1];
      #pragma unroll
      for (int i = 0; i < 8; ++i)
        acc[i] = __builtin_amdgcn_mfma_f32_16x16x32_f16(af.h, wf[i][4 + kk], acc[i], 0, 0, 0);
    }

    // 6) scatter acc -> wave-local s_g region (no barrier: same-wave reuse)
    #pragma unroll
    for (int slot = 0; slot < 8; ++slot) {
      const int colw = (slot >> 1) * 32 + (slot & 1) * 16 + pt; // pt = lane&15
      #pragma unroll
      for (int r = 0; r < 4; ++r)
        s_g[w * 2112 + (jg * 4 + r) * 132 + colw] = acc[slot][r];
    }

    // 6b) y consume (block0, wave0, lanes 0-15): value arrived alongside
    //     the h polls; expected zero spin iterations. Plain store to y.
    if (ylane && !b && t >= 2) {
      int ytr = 0;
      while (ypk == SENT && ++ytr < (1 << 18))
        ypk = __hip_atomic_load(&g_yx[((size_t)(t - 2) * NCL + c) * 16 + pt],
                                __ATOMIC_RELAXED, __HIP_MEMORY_SCOPE_AGENT);
      if (n_pt < NGRID)
        y[(size_t)(t - 2) * NGRID + n_pt] =
            yo + __uint_as_float((unsigned)ypk) + bo;
    }
    if (ylane && !b && t >= 1) yo = own4;

    // 7) cell update for this lane's 8 dims (wave-local gates; lgkm only)
    {
      const float* gp = &s_g[w * 2112 + pt * 132 + jg * 8];
      union { u64 u[2]; _Float16 h[8]; } pub;
      float yp = 0.f;
      #pragma unroll
      for (int j = 0; j < 8; ++j) {
        const float gi = gp[j]      + (float)gxr[0][j];
        const float gf = gp[32 + j] + (float)gxr[1][j];
        const float gg = gp[64 + j] + (float)gxr[2][j];
        const float go = gp[96 + j] + (float)gxr[3][j];
        const float i_ = fsig(gi);
        const float f_ = fsig(gf);
        const float g_ = ftanh(gg);
        const float o_ = fsig(go);
        cs[j] = f_ * cs[j] + i_ * g_;
        const float h = o_ * ftanh(cs[j]);
        pub.h[j] = (_Float16)h;
        yp += wo[j] * h;
      }
      // 8) publish wave's ks slice (2 coalesced 512B stores) + own-half LDS
      if (t < NT - 1) {
        u64* dst = g_hx + ((size_t)(t + 1) * NCL + c) * 1024 + (b * 4 + w) * 64 + l;
        __hip_atomic_store(dst,       pub.u[0], __ATOMIC_RELAXED, __HIP_MEMORY_SCOPE_AGENT);
        __hip_atomic_store(dst + 512, pub.u[1], __ATOMIC_RELAXED, __HIP_MEMORY_SCOPE_AGENT);
      }
      s_h[nxt][w * 64 + l]       = pub.u[0];
      s_h[nxt][512 + w * 64 + l] = pub.u[1];
      // 9) y: reduce partial over the 4 jg-lanes of this pt -> LDS (no atomics)
      yp += __shfl_xor(yp, 16);
      yp += __shfl_xor(yp, 32);
      if (jg == 0) s_y[cur][w][pt] = yp;
    }
    __syncthreads(); // single barrier: s_h(t+1) + s_y(t) complete across waves
  }

  // ---- y epilogue: fold step NT-1; block1 publishes it, block0 drains the
  // last two y rows (peer publishes NT-1 in its own epilogue; short spin).
  if (ylane) {
    const int par = (NT - 1) & 1;
    const float own4 = s_y[par][0][pt] + s_y[par][1][pt] +
                       s_y[par][2][pt] + s_y[par][3][pt];
    if (b) {
      __hip_atomic_store(&g_yx[((size_t)(NT - 1) * NCL + c) * 16 + pt],
                         (u64)__float_as_uint(own4),
                         __ATOMIC_RELAXED, __HIP_MEMORY_SCOPE_AGENT);
    } else {
      u64 v = SENT; int tr = 0;
      while (v == SENT && ++tr < (1 << 20))
        v = __hip_atomic_load(&g_yx[((size_t)(NT - 2) * NCL + c) * 16 + pt],
                              __ATOMIC_RELAXED, __HIP_MEMORY_SCOPE_AGENT);
      if (n_pt < NGRID)
        y[(size_t)(NT - 2) * NGRID + n_pt] = yo + __uint_as_float((unsigned)v) + bo;
      v = SENT; tr = 0;
      while (v == SENT && ++tr < (1 << 20))
        v = __hip_atomic_load(&g_yx[((size_t)(NT - 1) * NCL + c) * 16 + pt],
                              __ATOMIC_RELAXED, __HIP_MEMORY_SCOPE_AGENT);
      if (n_pt < NGRID)
        y[(size_t)(NT - 1) * NGRID + n_pt] = own4 + __uint_as_float((unsigned)v) + bo;
    }
  }
}

extern "C" void kernel_launch(void* const* d_in, const int* in_sizes, int n_in,
                              void* d_out, int out_size, void* d_ws, size_t ws_size,
                              hipStream_t stream) {
  (void)in_sizes; (void)n_in; (void)out_size; (void)d_ws; (void)ws_size;
  const float* x     = (const float*)d_in[0];
  // d_in[1] = wt_ih (zeros in eval mode, unused)
  const float* W_in  = (const float*)d_in[2];
  const float* b_in  = (const float*)d_in[3];
  const float* W_ih  = (const float*)d_in[4];
  const float* W_hh  = (const float*)d_in[5];
  const float* b_ih  = (const float*)d_in[6];
  const float* b_hh  = (const float*)d_in[7];
  const float* W_out = (const float*)d_in[8];
  const float* b_out = (const float*)d_in[9];
  float* y           = (float*)d_out;

  const int init_blocks = (int)((HX_TOT / 2 + 255) / 256);
  hipLaunchKernelGGL(init_kernel, dim3(init_blocks), dim3(256), 0, stream);
  hipLaunchKernelGGL(pack_wf_kernel, dim3(256), dim3(256), 0, stream, W_ih, W_hh);
  hipLaunchKernelGGL(gx_kernel, dim3(MBLK), dim3(256), 0, stream,
                     x, W_in, b_in, b_ih, b_hh);
  hipLaunchKernelGGL(rec_kernel, dim3(NCL * 2), dim3(256), 0, stream, W_out, b_out, y);
}